// Round 9
// baseline (488.493 us; speedup 1.0000x reference)
//
#include <hip/hip_runtime.h>
#include <hip/hip_bf16.h>

#define NNODES 50000
#define NEDGES 320000
#define EMB 128
#define DIN 192
#define NB 3
#define LAM 0.01f
#define LN_EPS 1e-5f
#define PI_F 3.14159265358979323846f

#define SCAN_B 196                        // 196*256 = 50176 >= NNODES
#define SCAN_N (SCAN_B * 256)

#define TILES (NEDGES / 64)               // 5000
#define EGRID 250                         // persistent blocks (1/CU resident)
#define EITER (TILES / EGRID)             // 20, exact

typedef __attribute__((ext_vector_type(8))) short v8s;
typedef __attribute__((ext_vector_type(4))) float v4f;
typedef __attribute__((ext_vector_type(2))) float v2f;
typedef __attribute__((ext_vector_type(2))) unsigned v2u;

// ---- workspace layout (4B-unit offsets) ----
#define WS_ESUM 0
#define WS_WB   16                        // Wb bf16 [3][6][16][64][8]
#define WS_G2B  (WS_WB + 73728)           // G2b bf16 [3][8][8][64][8]
#define WS_G2   (WS_G2B + 49152)          // G2 fp32 [768][128]
#define WS_PHI  (WS_G2 + 98304)           // Phi [768][128]
#define WS_M    (WS_PHI + 98304)          // M [128][128]
#define WS_BB   (WS_M + 16384)            // bb [768]
#define WS_GB2  (WS_BB + 768)             // g_b2 [128]
#define WS_CK   (WS_GB2 + 128)            // c_k [3][128]
#define WS_EN   (WS_CK + 384)             // energies [NE]
#define WS_NORM (WS_EN + NEDGES)          // node norms [NN]
#define WS_CNT  (WS_NORM + NNODES)        // int counts/scanned [SCAN_N]
#define WS_CUR  (WS_CNT + SCAN_N)         // int cursors [SCAN_N]
#define WS_PART (WS_CUR + SCAN_N)         // int block partials [256]
#define WS_EIDS (WS_PART + 256)           // int sorted edge ids [NE]
#define WS_LWB  (WS_EIDS + NEDGES)        // lin_w bf16 frags [4][8][64][8]

__device__ __forceinline__ unsigned pk2(float a, float b) {
  __hip_bfloat162 h2 = __float22bfloat162_rn(make_float2(a, b));
  return *reinterpret_cast<unsigned*>(&h2);
}

__device__ __forceinline__ void atomic2(float* dp, float a, float b) {
#if __has_builtin(__builtin_amdgcn_flat_atomic_fadd_v2f32)
  v2f val; val.x = a; val.y = b;
  __builtin_amdgcn_flat_atomic_fadd_v2f32((v2f*)dp, val);
#else
  atomicAdd(dp, a); atomicAdd(dp + 1, b);
#endif
}

// Raw workgroup barrier with LDS-only drain: keeps prefetch global loads
// (register destinations) in flight across the barrier. Safe: k_edges never
// communicates between threads through GLOBAL memory within the kernel.
__device__ __forceinline__ void bar_lds() {
  asm volatile("s_waitcnt lgkmcnt(0)" ::: "memory");
  __builtin_amdgcn_s_barrier();
  asm volatile("" ::: "memory");
}

// ---- P1: wfull(576) | m(64) | lwb(64) | phi(384) | norms+zero-out(12500) |
//          zero cnt(196) | zero esum(1)   -> grid 13785
__global__ __launch_bounds__(256) void k_prep1(
    const float* __restrict__ r1, const float* __restrict__ i1,
    __hip_bfloat16* __restrict__ Wb, const float* __restrict__ comb_w,
    const float* __restrict__ lin_w, float* __restrict__ M,
    const float* __restrict__ fre_w, float* __restrict__ Phi,
    const float* __restrict__ hidden, float* __restrict__ norms,
    float* __restrict__ outz, int* __restrict__ cnt, float* __restrict__ esum,
    __hip_bfloat16* __restrict__ lwb) {
  __shared__ float cs[384], sn[384];
  const int t = threadIdx.x;
  const int b = blockIdx.x;
  if (b < 576) {
    // Wb in MFMA B-frag order
    if (t < 192) sincosf((2.f * PI_F / 192.f) * (float)t, &sn[t], &cs[t]);
    __syncthreads();
    int idx = b * 256 + t;                         // 147456 total
    int n = idx / 768, c = idx - (idx / 768) * 768;
    int k = c >> 8, col = c & 255;
    int isI = col >> 7, j = col & 127;
    const float* ap = (isI ? i1 : r1) + (size_t)k * DIN * EMB + j;
    const float* bp = (isI ? r1 : i1) + (size_t)k * DIN * EMB + j;
    float sgn = isI ? -1.f : 1.f;
    float acc = 0.f;
    int m = 0;
    for (int f = 0; f < DIN; ++f) {
      acc = fmaf(cs[m], ap[(size_t)f * EMB], fmaf(sgn * sn[m], bp[(size_t)f * EMB], acc));
      m += n; if (m >= 192) m -= 192;
    }
    int kc = n >> 5, quad = (n & 31) >> 3, jj = n & 7;
    int lane = quad * 16 + (col & 15);
    Wb[((((k * 6 + kc) * 16 + (col >> 4)) * 64) + lane) * 8 + jj] = __float2bfloat16(acc);
  } else if (b < 640) {
    // M[j][j2] = sum_t comb_w[2j][t] * lin_w[t][j2]
    int idx = (b - 576) * 256 + t;                 // 16384
    int j = idx >> 7, j2 = idx & 127;
    float acc = 0.f;
    for (int tt = 0; tt < 128; ++tt)
      acc = fmaf(comb_w[(2 * j) * 128 + tt], lin_w[tt * 128 + j2], acc);
    M[idx] = acc;
  } else if (b < 704) {
    // lin_w -> bf16 B-frag layout [4 kc][8 colTile][64 lane][8 jj]
    int idx = (b - 640) * 256 + t;                 // 16384
    int kk = idx >> 7, col = idx & 127;
    int kc = kk >> 5, quad2 = (kk & 31) >> 3, jj = kk & 7;
    lwb[(((kc * 8 + (col >> 4)) * 64) + quad2 * 16 + (col & 15)) * 8 + jj] =
        __float2bfloat16(lin_w[kk * 128 + col]);
  } else if (b < 1088) {
    // Phi
    for (int i = t; i < 384; i += 256)
      sincosf((2.f * PI_F / 384.f) * (float)i, &sn[i], &cs[i]);
    __syncthreads();
    int idx = (b - 704) * 256 + t;                 // 98304
    int slot = idx >> 7, j1 = idx & 127;
    int k = slot >> 8, r = slot & 255;
    int isI = r >> 7;
    int f = k * 128 + (r & 127);
    const float* tp = isI ? sn : cs;
    float sg = isI ? -1.f : 1.f;
    float acc = 0.f;
    int m = 0;
    for (int n = 0; n < 384; ++n) {
      acc = fmaf(sg * tp[m], fre_w[n * 128 + j1], acc);
      m += f; if (m >= 384) m -= 384;
    }
    Phi[slot * 128 + j1] = acc * (1.f / 384.f);
  } else if (b < 13588) {
    // per-node ||hidden[n]||^2 + zero the accumulator
    const int w = t >> 6, lane = t & 63;
    const int n = (b - 1088) * 4 + w;              // 12500*4 = 50000
    const float2 v = ((const float2*)(hidden + (size_t)n * 128))[lane];
    float ss = v.x * v.x + v.y * v.y;
#pragma unroll
    for (int off = 32; off > 0; off >>= 1) ss += __shfl_xor(ss, off, 64);
    if (lane == 0) norms[n] = ss;
    float2 z; z.x = 0.f; z.y = 0.f;
    ((float2*)(outz + (size_t)n * 128))[lane] = z;
  } else if (b < 13784) {
    cnt[(b - 13588) * 256 + t] = 0;                // SCAN_N
  } else {
    if (t < 16) esum[t] = 0.f;
  }
}

// ---- P2: g2(384) | energy+hist(1250) ----
__global__ __launch_bounds__(256) void k_prep2(
    const float* __restrict__ Phi, const float* __restrict__ M,
    float* __restrict__ G2, __hip_bfloat16* __restrict__ G2b,
    const float* __restrict__ norms, const float* __restrict__ eattr,
    const float* __restrict__ ett, const int* __restrict__ eidx,
    float* __restrict__ energies, float* __restrict__ esum,
    int* __restrict__ cnt) {
  const int t = threadIdx.x;
  const int b = blockIdx.x;
  if (b < 384) {
    int idx = b * 256 + t;                         // 98304
    int slot = idx >> 7, j2 = idx & 127;
    float acc = 0.f;
    for (int j1 = 0; j1 < 128; ++j1)
      acc = fmaf(Phi[slot * 128 + j1], M[j1 * 128 + j2], acc);
    G2[idx] = acc;
    int k = slot >> 8, s = slot & 255;
    int kc = s >> 5, quad = (s & 31) >> 3, jj = s & 7;
    G2b[((((k * 8 + kc) * 8 + (j2 >> 4)) * 64) + quad * 16 + (j2 & 15)) * 8 + jj] =
        __float2bfloat16(acc);
  } else {
    int e = (b - 384) * 256 + t;
    float ss = norms[eidx[e]];
    const float4* a4 = (const float4*)(eattr + (size_t)e * 32);
#pragma unroll
    for (int i = 0; i < 8; ++i) {
      float4 v = a4[i];
      ss += v.x * v.x + v.y * v.y + v.z * v.z + v.w * v.w;
    }
    const float4* t4 = (const float4*)(ett + (size_t)e * 32);
#pragma unroll
    for (int i = 0; i < 8; ++i) {
      float4 v = t4[i];
      ss += v.x * v.x + v.y * v.y + v.z * v.z + v.w * v.w;
    }
    float en = 192.f * ss;
    energies[e] = en;
    float tot = en;
#pragma unroll
    for (int off = 32; off > 0; off >>= 1) tot += __shfl_down(tot, off, 64);
    if ((t & 63) == 0) atomicAdd(esum, tot);
    atomicAdd(&cnt[eidx[NEDGES + e]], 1);          // histogram
  }
}

// ---- P3: small(5) | scanA(196) ----
__global__ __launch_bounds__(256) void k_prep3(
    const float* __restrict__ rb1, const float* __restrict__ ib1,
    const float* __restrict__ fre_b, const float* __restrict__ comb_b,
    const float* __restrict__ lin_w, const float* __restrict__ M,
    const float* __restrict__ G2, float* __restrict__ bb,
    float* __restrict__ gb2, float* __restrict__ ck,
    int* __restrict__ cnt, int* __restrict__ part) {
  __shared__ int sm[256];
  const int t = threadIdx.x;
  const int b = blockIdx.x;
  if (b < 5) {
    int idx = b * 256 + t;                         // 1280
    if (idx < 768) {
      int k = idx >> 8, r = idx & 255;
      bb[idx] = (r >= 128) ? ib1[k * 128 + (r & 127)] : rb1[k * 128 + r];
    } else if (idx < 896) {
      int j2 = idx - 768;
      float acc = 0.f;
      for (int j = 0; j < 128; ++j) acc += fre_b[j] * M[j * 128 + j2];
      for (int tt = 0; tt < 128; ++tt) acc += comb_b[tt] * lin_w[tt * 128 + j2];
      gb2[j2] = acc;
    } else if (idx < 1280) {
      int q = idx - 896;
      int k = q >> 7, j2 = q & 127;
      float acc = 0.f;
      for (int j = 0; j < 128; ++j) {
        float vr = rb1[k * 128 + j];
        vr = fmaxf(vr, 0.f); vr = (vr > LAM) ? vr - LAM : 0.f;
        float vi = ib1[k * 128 + j];
        vi = fmaxf(vi, 0.f); vi = (vi > LAM) ? vi - LAM : 0.f;
        acc += vr * G2[(k * 256 + j) * 128 + j2] + vi * G2[(k * 256 + 128 + j) * 128 + j2];
      }
      ck[k * 128 + j2] = acc;
    }
  } else {
    int blk = b - 5;
    int i = blk * 256 + t;
    int v = (i < NNODES) ? cnt[i] : 0;
    sm[t] = v;
    __syncthreads();
#pragma unroll
    for (int off = 1; off < 256; off <<= 1) {
      int x = (t >= off) ? sm[t - off] : 0;
      __syncthreads();
      sm[t] += x;
      __syncthreads();
    }
    cnt[i] = sm[t] - v;                            // exclusive, in place
    if (t == 255) part[blk] = sm[t];
  }
}

// fused scanB+scanC
__global__ __launch_bounds__(256) void k_scan(const int* __restrict__ cnt,
                                              const int* __restrict__ part,
                                              int* __restrict__ cur) {
  __shared__ int sm[256];
  const int t = threadIdx.x;
  const int b = blockIdx.x;
  sm[t] = (t < b) ? part[t] : 0;
  __syncthreads();
#pragma unroll
  for (int off = 128; off > 0; off >>= 1) {
    if (t < off) sm[t] += sm[t + off];
    __syncthreads();
  }
  cur[b * 256 + t] = cnt[b * 256 + t] + sm[0];
}

__global__ __launch_bounds__(256) void k_fill(const int* __restrict__ eidx,
                                              int* __restrict__ cur,
                                              int* __restrict__ eids) {
  int e = blockIdx.x * 256 + threadIdx.x;
  int pos = atomicAdd(&cur[eidx[NEDGES + e]], 1);
  eids[pos] = e;
}

// ---- main edge kernel: persistent 250x20, software-pipelined, swapped MFMAs.
// R8: stage-A X-fragments (af) are band-invariant -> hoisted to registers,
// loaded ONCE per tile (24 v8s = 96 VGPR). Band loop stage A = global bfr
// loads + MFMA only (no LDS reads). Cuts LDS read traffic ~29% (the R7
// counters showed LDS-read throughput is the binding pipe: 18.5K cy/tile
// vs 17.5K modeled from 1.36MB/tile LDS reads at 85 B/cy/CU).
#define XS_STR 200
#define OS_STR 264
#define ZS_STR 132

#define LOADM_PUBLISH(B)                                                       \
  do {                                                                         \
    if (t < 3) tileact[B][t] = 0;                                              \
    if (t < 64) {                                                              \
      eid_s[B][t] = eidA;                                                      \
      srcs[B][t] = srcA;                                                       \
      dsts[B][t] = dstA;                                                       \
      _Pragma("unroll") for (int k = 0; k < NB; ++k) {                         \
        bool m_ = (enA >= lo[k]) && (enA <= hi[k]);                            \
        maskf[B][k][t] = m_ ? 1.f : 0.f;                                       \
        if (m_) atomicOr(&tileact[B][k], 1);                                   \
      }                                                                        \
    }                                                                          \
  } while (0)

#define GATHER(B)                                                              \
  do {                                                                         \
    const int eh = t >> 5, ch = (t & 31) * 4;                                  \
    hr0 = *(const float4*)(hidden + (size_t)srcs[B][eh] * 128 + ch);           \
    hr1 = *(const float4*)(hidden + (size_t)srcs[B][eh + 16] * 128 + ch);      \
    hr2 = *(const float4*)(hidden + (size_t)srcs[B][eh + 32] * 128 + ch);      \
    hr3 = *(const float4*)(hidden + (size_t)srcs[B][eh + 48] * 128 + ch);      \
    const int ea = t >> 4, q = t & 15;                                         \
    const float* p0 = (q < 8) ? eattr + (size_t)eid_s[B][ea] * 32 + q * 4      \
                              : ett + (size_t)eid_s[B][ea] * 32 + (q - 8) * 4; \
    ar0 = *(const float4*)p0;                                                  \
    const float* p1 = (q < 8) ? eattr + (size_t)eid_s[B][ea + 32] * 32 + q * 4 \
                              : ett + (size_t)eid_s[B][ea + 32] * 32 + (q - 8) * 4; \
    ar1 = *(const float4*)p1;                                                  \
  } while (0)

#define WRITEX()                                                               \
  do {                                                                         \
    const int eh = t >> 5, ch = (t & 31) * 4;                                  \
    v2u u;                                                                     \
    u.x = pk2(hr0.x, hr0.y); u.y = pk2(hr0.z, hr0.w);                          \
    *(v2u*)&Xs[eh * XS_STR + ch] = u;                                          \
    u.x = pk2(hr1.x, hr1.y); u.y = pk2(hr1.z, hr1.w);                          \
    *(v2u*)&Xs[(eh + 16) * XS_STR + ch] = u;                                   \
    u.x = pk2(hr2.x, hr2.y); u.y = pk2(hr2.z, hr2.w);                          \
    *(v2u*)&Xs[(eh + 32) * XS_STR + ch] = u;                                   \
    u.x = pk2(hr3.x, hr3.y); u.y = pk2(hr3.z, hr3.w);                          \
    *(v2u*)&Xs[(eh + 48) * XS_STR + ch] = u;                                   \
    const int ea = t >> 4, q4 = (t & 15) * 4;                                  \
    u.x = pk2(ar0.x, ar0.y); u.y = pk2(ar0.z, ar0.w);                          \
    *(v2u*)&Xs[ea * XS_STR + 128 + q4] = u;                                    \
    u.x = pk2(ar1.x, ar1.y); u.y = pk2(ar1.z, ar1.w);                          \
    *(v2u*)&Xs[(ea + 32) * XS_STR + 128 + q4] = u;                             \
  } while (0)

__global__ __launch_bounds__(512, 2) void k_edges(
    const float* __restrict__ hidden, const float* __restrict__ eattr,
    const float* __restrict__ ett, const float* __restrict__ alpha,
    const int* __restrict__ eidx, const int* __restrict__ eids,
    const __hip_bfloat16* __restrict__ Wb, const __hip_bfloat16* __restrict__ G2b,
    const float* __restrict__ bb, const float* __restrict__ gb2,
    const float* __restrict__ ck, const float* __restrict__ energies,
    const float* __restrict__ esum, float* __restrict__ accum) {
  __shared__ __align__(16) char smem[64 * XS_STR * 2 + 64 * OS_STR * 2];
  short* Xs = (short*)smem;
  short* Os = (short*)(smem + 64 * XS_STR * 2);
  float* Zs = (float*)smem;                        // 64*132*4 = 33792 B
  __shared__ float maskf[2][3][64];
  __shared__ int eid_s[2][64], srcs[2][64], dsts[2][64];
  __shared__ int tileact[2][3];

  const int t = threadIdx.x;
  const int lane = t & 63, w = t >> 6;
  const int quad = lane >> 4, lc = lane & 15;
  const int tile = blockIdx.x;

  float lo[NB], hi[NB];
  {
    const float es = *esum;
#pragma unroll
    for (int k = 0; k < NB; ++k) {
      float a = alpha[k];
      float factor = (2.f * (k + 1) - 1.f) / (2.f * NB);
      float Q = a * factor * es;
      float bw = es / (a * (2.f * NB));
      lo[k] = Q - bw;
      hi[k] = Q + bw;
    }
  }

  float4 hr0, hr1, hr2, hr3, ar0, ar1;
  int eidA = 0, srcA = 0, dstA = 0, eidB = 0;
  float enA = 0.f;

  // prologue: meta(tile0) -> buf0; meta(tile1) -> regs; eid(tile2) -> reg
  if (t < 64) {
    int e_ = eids[tile * 64 + t];
    eidA = e_; srcA = eidx[e_]; dstA = eidx[NEDGES + e_]; enA = energies[e_];
  }
  LOADM_PUBLISH(0);
  if (t < 64) {
    int e_ = eids[(tile + EGRID) * 64 + t];
    eidA = e_; srcA = eidx[e_]; dstA = eidx[NEDGES + e_]; enA = energies[e_];
    eidB = eids[(tile + 2 * EGRID) * 64 + t];
  }
  bar_lds();
  GATHER(0);

#pragma unroll 1
  for (int ti = 0; ti < EITER; ++ti) {
    const int cb = ti & 1;
    WRITEX();
    if (ti + 1 < EITER) LOADM_PUBLISH(cb ^ 1);
    if (t < 64) {
      if (ti + 2 < EITER) {
        eidA = eidB;
        srcA = eidx[eidB]; dstA = eidx[NEDGES + eidB]; enA = energies[eidB];
      }
      if (ti + 3 < EITER)
        eidB = eids[(tile + (ti + 3) * EGRID) * 64 + t];
    }
    bar_lds();

    // ---- hoisted A-fragments: read Xs ONCE per tile (band-invariant) ----
    v8s af[6][4];
#pragma unroll
    for (int kc = 0; kc < 6; ++kc)
#pragma unroll
      for (int mt = 0; mt < 4; ++mt)
        af[kc][mt] = *(const v8s*)&Xs[(mt * 16 + lc) * XS_STR + kc * 32 + quad * 8];

    v4f acc2[4];                                   // cols w*16+quad*4..
#pragma unroll
    for (int mt = 0; mt < 4; ++mt)
#pragma unroll
      for (int r = 0; r < 4; ++r) acc2[mt][r] = 0.f;

    for (int k = 0; k < NB; ++k) {
      if (!tileact[cb][k]) continue;               // block-uniform
      v4f accA[4][2];
#pragma unroll
      for (int mt = 0; mt < 4; ++mt)
#pragma unroll
        for (int n = 0; n < 2; ++n)
#pragma unroll
          for (int r = 0; r < 4; ++r) accA[mt][n][r] = 0.f;

      // stage A (swapped, reg-resident af): no LDS reads here
#pragma unroll
      for (int kc = 0; kc < 6; ++kc) {
        const __hip_bfloat16* wp = Wb + ((((k * 6 + kc) * 16 + 2 * w) * 64) + lane) * 8;
#pragma unroll
        for (int ntl = 0; ntl < 2; ++ntl) {
          v8s bfr = *(const v8s*)(const void*)(wp + ntl * 512);
#pragma unroll
          for (int mt = 0; mt < 4; ++mt)
            accA[mt][ntl] =
                __builtin_amdgcn_mfma_f32_16x16x32_bf16(bfr, af[kc][mt], accA[mt][ntl], 0, 0, 0);
        }
      }
      bar_lds();  // protect Os WAR vs previous band's stage B reads
      // nonlinearity -> Os (4 consecutive bf16 cols per lane -> b64 writes)
#pragma unroll
      for (int mt = 0; mt < 4; ++mt) {
        const float mk = maskf[cb][k][mt * 16 + lc];
#pragma unroll
        for (int ntl = 0; ntl < 2; ++ntl) {
          const int colb = w * 32 + ntl * 16 + quad * 4;
          const float4 bbv = *(const float4*)&bb[k * 256 + colb];
          float v0 = fmaf(mk, accA[mt][ntl][0], bbv.x);
          float v1 = fmaf(mk, accA[mt][ntl][1], bbv.y);
          float v2 = fmaf(mk, accA[mt][ntl][2], bbv.z);
          float v3 = fmaf(mk, accA[mt][ntl][3], bbv.w);
          v0 = fmaxf(v0, 0.f); v0 = (v0 > LAM) ? v0 - LAM : 0.f;
          v1 = fmaxf(v1, 0.f); v1 = (v1 > LAM) ? v1 - LAM : 0.f;
          v2 = fmaxf(v2, 0.f); v2 = (v2 > LAM) ? v2 - LAM : 0.f;
          v3 = fmaxf(v3, 0.f); v3 = (v3 > LAM) ? v3 - LAM : 0.f;
          v2u u; u.x = pk2(v0, v1); u.y = pk2(v2, v3);
          *(v2u*)&Os[(mt * 16 + lc) * OS_STR + colb] = u;
        }
      }
      bar_lds();
      // stage B (swapped, unsplit): wave w -> col-tile w, all 64 edges
#pragma unroll
      for (int kc = 0; kc < 8; ++kc) {
        v8s of[4];
#pragma unroll
        for (int mt = 0; mt < 4; ++mt)
          of[mt] = *(const v8s*)&Os[(mt * 16 + lc) * OS_STR + kc * 32 + quad * 8];
        v8s g = *(const v8s*)(const void*)(
            G2b + ((((k * 8 + kc) * 8 + w) * 64) + lane) * 8);
#pragma unroll
        for (int mt = 0; mt < 4; ++mt)
          acc2[mt] = __builtin_amdgcn_mfma_f32_16x16x32_bf16(g, of[mt], acc2[mt], 0, 0, 0);
      }
    }

    // prefetch next tile's gather; epilogue is the latency cover
    if (ti + 1 < EITER) GATHER(cb ^ 1);

    // ---- epilogue: z -> Zs (b128 writes), segmented reduce (4 waves) + atomics
    bar_lds();
    {
      const int colb = w * 16 + quad * 4;
      float4 base = *(const float4*)&gb2[colb];
#pragma unroll
      for (int k = 0; k < NB; ++k)
        if (!tileact[cb][k]) {
          const float4 cv = *(const float4*)&ck[k * 128 + colb];
          base.x += cv.x; base.y += cv.y; base.z += cv.z; base.w += cv.w;
        }
#pragma unroll
      for (int mt = 0; mt < 4; ++mt) {
        const int rowz = mt * 16 + lc;
        float4 zz;
        zz.x = acc2[mt][0] + base.x;
        zz.y = acc2[mt][1] + base.y;
        zz.z = acc2[mt][2] + base.z;
        zz.w = acc2[mt][3] + base.w;
        *(float4*)&Zs[rowz * ZS_STR + colb] = zz;
      }
    }
    bar_lds();
    if (w < 4) {
      int c = 2 * lane;
      int r0 = w * 16;
      float s0 = 0.f, s1 = 0.f;
#pragma unroll
      for (int r = 0; r < 16; ++r) {
        int row = r0 + r;
        const float2 z = *(const float2*)&Zs[row * ZS_STR + c];
        s0 += z.x; s1 += z.y;
        int d = dsts[cb][row];
        if (r == 15 || dsts[cb][row + 1] != d) {
          atomic2(accum + (size_t)d * 128 + c, s0, s1);
          s0 = 0.f; s1 = 0.f;
        }
      }
    }
    if (ti + 1 < EITER) bar_lds();                 // Zs reads done before next WRITEX
  }
}

// node kernel: MFMA bf16 boundary@lin_w (+edge accum +lin_b) -> LN -> relu.
__global__ __launch_bounds__(256) void k_nodes(
    const float* __restrict__ boundary, const __hip_bfloat16* __restrict__ lwb,
    const float* __restrict__ lin_b, const float* __restrict__ ln_g,
    const float* __restrict__ ln_b, float* __restrict__ out) {
  __shared__ __align__(16) short Bs[64 * 136];     // 17408 B
  __shared__ __align__(16) float Zs[64 * 132];     // 33792 B
  const int t = threadIdx.x;
  const int w = t >> 6, lane = t & 63;
  const int quad = lane >> 4, lc = lane & 15;
  const int n0 = blockIdx.x * 64;
  // stage boundary -> bf16 (rows beyond NNODES zeroed)
#pragma unroll
  for (int it = 0; it < 8; ++it) {
    int fi = it * 256 + t;                         // 2048 float4 slots
    int row = fi >> 5, c4 = fi & 31;
    float4 v = make_float4(0.f, 0.f, 0.f, 0.f);
    if (n0 + row < NNODES)
      v = *(const float4*)(boundary + (size_t)(n0 + row) * 128 + c4 * 4);
    v2u u; u.x = pk2(v.x, v.y); u.y = pk2(v.z, v.w);
    *(v2u*)&Bs[row * 136 + c4 * 4] = u;
  }
  __syncthreads();
  const int we = w >> 1, wc = w & 1;               // 32 rows x 64 cols per wave
  v4f acc[2][4];
#pragma unroll
  for (int m2 = 0; m2 < 2; ++m2)
#pragma unroll
    for (int ct = 0; ct < 4; ++ct)
#pragma unroll
      for (int r = 0; r < 4; ++r) acc[m2][ct][r] = 0.f;
#pragma unroll
  for (int kc = 0; kc < 4; ++kc) {
    v8s b0 = *(const v8s*)&Bs[(we * 32 + lc) * 136 + kc * 32 + quad * 8];
    v8s b1 = *(const v8s*)&Bs[(we * 32 + 16 + lc) * 136 + kc * 32 + quad * 8];
#pragma unroll
    for (int ct = 0; ct < 4; ++ct) {
      v8s af = *(const v8s*)(const void*)(
          lwb + (((kc * 8 + (wc * 4 + ct)) * 64) + lane) * 8);
      acc[0][ct] = __builtin_amdgcn_mfma_f32_16x16x32_bf16(af, b0, acc[0][ct], 0, 0, 0);
      acc[1][ct] = __builtin_amdgcn_mfma_f32_16x16x32_bf16(af, b1, acc[1][ct], 0, 0, 0);
    }
  }
#pragma unroll
  for (int m2 = 0; m2 < 2; ++m2)
#pragma unroll
    for (int ct = 0; ct < 4; ++ct) {
      const int colb = wc * 64 + ct * 16 + quad * 4;
      const int row = we * 32 + m2 * 16 + lc;
      float4 z;
      z.x = acc[m2][ct][0]; z.y = acc[m2][ct][1];
      z.z = acc[m2][ct][2]; z.w = acc[m2][ct][3];
      *(float4*)&Zs[row * 132 + colb] = z;
    }
  __syncthreads();
  // LN: wave handles 16 nodes; lane owns cols 2*lane, 2*lane+1
  const int c = 2 * lane;
  const float2 lb = *(const float2*)&lin_b[c];
  const float2 gg = *(const float2*)&ln_g[c];
  const float2 bbv = *(const float2*)&ln_b[c];
#pragma unroll 1
  for (int i = 0; i < 16; ++i) {
    int row = w * 16 + i;
    int n = n0 + row;
    if (n >= NNODES) break;
    const float2 z = *(const float2*)&Zs[row * 132 + c];
    const float2 ob = *(const float2*)&out[(size_t)n * 128 + c];
    float a0 = z.x + ob.x + lb.x;
    float a1 = z.y + ob.y + lb.y;
    float s = a0 + a1, sq = a0 * a0 + a1 * a1;
#pragma unroll
    for (int off = 32; off > 0; off >>= 1) {
      s += __shfl_xor(s, off, 64);
      sq += __shfl_xor(sq, off, 64);
    }
    float mu = s * (1.f / 128.f);
    float var = sq * (1.f / 128.f) - mu * mu;
    float rs = 1.f / sqrtf(var + LN_EPS);
    float2 o;
    o.x = fmaxf((a0 - mu) * rs * gg.x + bbv.x, 0.f);
    o.y = fmaxf((a1 - mu) * rs * gg.y + bbv.y, 0.f);
    *(float2*)&out[(size_t)n * 128 + c] = o;
  }
}

extern "C" void kernel_launch(void* const* d_in, const int* in_sizes, int n_in,
                              void* d_out, int out_size, void* d_ws, size_t ws_size,
                              hipStream_t stream) {
  const float* hidden   = (const float*)d_in[0];
  const float* eattr    = (const float*)d_in[1];
  const float* ett      = (const float*)d_in[2];
  const float* boundary = (const float*)d_in[3];
  const float* alpha    = (const float*)d_in[4];
  const float* r1       = (const float*)d_in[5];
  const float* i1       = (const float*)d_in[6];
  const float* rb1      = (const float*)d_in[7];
  const float* ib1      = (const float*)d_in[8];
  const float* fre_w    = (const float*)d_in[9];
  const float* fre_b    = (const float*)d_in[10];
  const float* comb_w   = (const float*)d_in[11];
  const float* comb_b   = (const float*)d_in[12];
  const float* lin_w    = (const float*)d_in[13];
  const float* lin_b    = (const float*)d_in[14];
  const float* ln_g     = (const float*)d_in[15];
  const float* ln_b     = (const float*)d_in[16];
  const int*   eidx     = (const int*)d_in[17];
  float* ws  = (float*)d_ws;
  float* out = (float*)d_out;
  __hip_bfloat16* Wb  = (__hip_bfloat16*)(ws + WS_WB);
  __hip_bfloat16* G2b = (__hip_bfloat16*)(ws + WS_G2B);
  __hip_bfloat16* lwb = (__hip_bfloat16*)(ws + WS_LWB);
  int* cnt  = (int*)(ws + WS_CNT);
  int* cur  = (int*)(ws + WS_CUR);
  int* part = (int*)(ws + WS_PART);
  int* eids = (int*)(ws + WS_EIDS);

  k_prep1<<<13785, 256, 0, stream>>>(r1, i1, Wb, comb_w, lin_w, ws + WS_M,
                                     fre_w, ws + WS_PHI, hidden, ws + WS_NORM,
                                     out, cnt, ws + WS_ESUM, lwb);
  k_prep2<<<384 + NEDGES / 256, 256, 0, stream>>>(ws + WS_PHI, ws + WS_M, ws + WS_G2,
                                                  G2b, ws + WS_NORM, eattr, ett, eidx,
                                                  ws + WS_EN, ws + WS_ESUM, cnt);
  k_prep3<<<5 + SCAN_B, 256, 0, stream>>>(rb1, ib1, fre_b, comb_b, lin_w, ws + WS_M,
                                          ws + WS_G2, ws + WS_BB, ws + WS_GB2,
                                          ws + WS_CK, cnt, part);
  k_scan<<<SCAN_B, 256, 0, stream>>>(cnt, part, cur);
  k_fill<<<NEDGES / 256, 256, 0, stream>>>(eidx, cur, eids);
  k_edges<<<EGRID, 512, 0, stream>>>(hidden, eattr, ett, alpha, eidx, eids,
                                     Wb, G2b, ws + WS_BB, ws + WS_GB2,
                                     ws + WS_CK, ws + WS_EN, ws + WS_ESUM, out);
  k_nodes<<<(NNODES + 63) / 64, 256, 0, stream>>>(boundary, lwb, lin_b, ln_g, ln_b, out);
}

// Round 11
// 458.308 us; speedup vs baseline: 1.0659x; 1.0659x over previous
//
#include <hip/hip_runtime.h>
#include <hip/hip_bf16.h>

#define NNODES 50000
#define NEDGES 320000
#define EMB 128
#define DIN 192
#define NB 3
#define LAM 0.01f
#define LN_EPS 1e-5f
#define PI_F 3.14159265358979323846f

#define SCAN_B 196                        // 196*256 = 50176 >= NNODES
#define SCAN_N (SCAN_B * 256)

#define TILES (NEDGES / 64)               // 5000
#define EGRID 250                         // persistent blocks (1/CU resident)
#define EITER (TILES / EGRID)             // 20, exact

typedef __attribute__((ext_vector_type(8))) short v8s;
typedef __attribute__((ext_vector_type(4))) float v4f;
typedef __attribute__((ext_vector_type(2))) float v2f;
typedef __attribute__((ext_vector_type(2))) unsigned v2u;

// ---- workspace layout (4B-unit offsets) ----
#define WS_ESUM 0
#define WS_WB   16                        // Wb bf16 [3][6][16][64][8]
#define WS_G2B  (WS_WB + 73728)           // G2b bf16 [3][8][8][64][8]
#define WS_G2   (WS_G2B + 49152)          // G2 fp32 [768][128]
#define WS_PHI  (WS_G2 + 98304)           // Phi [768][128]
#define WS_M    (WS_PHI + 98304)          // M [128][128]
#define WS_BB   (WS_M + 16384)            // bb [768]
#define WS_GB2  (WS_BB + 768)             // g_b2 [128]
#define WS_CK   (WS_GB2 + 128)            // c_k [3][128]
#define WS_EN   (WS_CK + 384)             // energies [NE]
#define WS_NORM (WS_EN + NEDGES)          // node norms [NN]
#define WS_CNT  (WS_NORM + NNODES)        // int counts/scanned [SCAN_N]
#define WS_CUR  (WS_CNT + SCAN_N)         // int cursors [SCAN_N]
#define WS_PART (WS_CUR + SCAN_N)         // int block partials [256]
#define WS_EIDS (WS_PART + 256)           // int sorted edge ids [NE]
#define WS_LWB  (WS_EIDS + NEDGES)        // lin_w bf16 frags [4][8][64][8]

__device__ __forceinline__ unsigned pk2(float a, float b) {
  __hip_bfloat162 h2 = __float22bfloat162_rn(make_float2(a, b));
  return *reinterpret_cast<unsigned*>(&h2);
}

__device__ __forceinline__ void atomic2(float* dp, float a, float b) {
#if __has_builtin(__builtin_amdgcn_flat_atomic_fadd_v2f32)
  v2f val; val.x = a; val.y = b;
  __builtin_amdgcn_flat_atomic_fadd_v2f32((v2f*)dp, val);
#else
  atomicAdd(dp, a); atomicAdd(dp + 1, b);
#endif
}

// Raw workgroup barrier with LDS-only drain: keeps prefetch global loads
// (register destinations) in flight across the barrier. Safe: k_edges never
// communicates between threads through GLOBAL memory within the kernel.
__device__ __forceinline__ void bar_lds() {
  asm volatile("s_waitcnt lgkmcnt(0)" ::: "memory");
  __builtin_amdgcn_s_barrier();
  asm volatile("" ::: "memory");
}

// ---- P1: wfull(576) | m(64) | lwb(64) | phi(384) | norms+zero-out(12500) |
//          zero cnt(196) | zero esum(1)   -> grid 13785
__global__ __launch_bounds__(256) void k_prep1(
    const float* __restrict__ r1, const float* __restrict__ i1,
    __hip_bfloat16* __restrict__ Wb, const float* __restrict__ comb_w,
    const float* __restrict__ lin_w, float* __restrict__ M,
    const float* __restrict__ fre_w, float* __restrict__ Phi,
    const float* __restrict__ hidden, float* __restrict__ norms,
    float* __restrict__ outz, int* __restrict__ cnt, float* __restrict__ esum,
    __hip_bfloat16* __restrict__ lwb) {
  __shared__ float cs[384], sn[384];
  const int t = threadIdx.x;
  const int b = blockIdx.x;
  if (b < 576) {
    // Wb in MFMA B-frag order
    if (t < 192) sincosf((2.f * PI_F / 192.f) * (float)t, &sn[t], &cs[t]);
    __syncthreads();
    int idx = b * 256 + t;                         // 147456 total
    int n = idx / 768, c = idx - (idx / 768) * 768;
    int k = c >> 8, col = c & 255;
    int isI = col >> 7, j = col & 127;
    const float* ap = (isI ? i1 : r1) + (size_t)k * DIN * EMB + j;
    const float* bp = (isI ? r1 : i1) + (size_t)k * DIN * EMB + j;
    float sgn = isI ? -1.f : 1.f;
    float acc = 0.f;
    int m = 0;
    for (int f = 0; f < DIN; ++f) {
      acc = fmaf(cs[m], ap[(size_t)f * EMB], fmaf(sgn * sn[m], bp[(size_t)f * EMB], acc));
      m += n; if (m >= 192) m -= 192;
    }
    int kc = n >> 5, quad = (n & 31) >> 3, jj = n & 7;
    int lane = quad * 16 + (col & 15);
    Wb[((((k * 6 + kc) * 16 + (col >> 4)) * 64) + lane) * 8 + jj] = __float2bfloat16(acc);
  } else if (b < 640) {
    // M[j][j2] = sum_t comb_w[2j][t] * lin_w[t][j2]
    int idx = (b - 576) * 256 + t;                 // 16384
    int j = idx >> 7, j2 = idx & 127;
    float acc = 0.f;
    for (int tt = 0; tt < 128; ++tt)
      acc = fmaf(comb_w[(2 * j) * 128 + tt], lin_w[tt * 128 + j2], acc);
    M[idx] = acc;
  } else if (b < 704) {
    // lin_w -> bf16 B-frag layout [4 kc][8 colTile][64 lane][8 jj]
    int idx = (b - 640) * 256 + t;                 // 16384
    int kk = idx >> 7, col = idx & 127;
    int kc = kk >> 5, quad2 = (kk & 31) >> 3, jj = kk & 7;
    lwb[(((kc * 8 + (col >> 4)) * 64) + quad2 * 16 + (col & 15)) * 8 + jj] =
        __float2bfloat16(lin_w[kk * 128 + col]);
  } else if (b < 1088) {
    // Phi
    for (int i = t; i < 384; i += 256)
      sincosf((2.f * PI_F / 384.f) * (float)i, &sn[i], &cs[i]);
    __syncthreads();
    int idx = (b - 704) * 256 + t;                 // 98304
    int slot = idx >> 7, j1 = idx & 127;
    int k = slot >> 8, r = slot & 255;
    int isI = r >> 7;
    int f = k * 128 + (r & 127);
    const float* tp = isI ? sn : cs;
    float sg = isI ? -1.f : 1.f;
    float acc = 0.f;
    int m = 0;
    for (int n = 0; n < 384; ++n) {
      acc = fmaf(sg * tp[m], fre_w[n * 128 + j1], acc);
      m += f; if (m >= 384) m -= 384;
    }
    Phi[slot * 128 + j1] = acc * (1.f / 384.f);
  } else if (b < 13588) {
    // per-node ||hidden[n]||^2 + zero the accumulator
    const int w = t >> 6, lane = t & 63;
    const int n = (b - 1088) * 4 + w;              // 12500*4 = 50000
    const float2 v = ((const float2*)(hidden + (size_t)n * 128))[lane];
    float ss = v.x * v.x + v.y * v.y;
#pragma unroll
    for (int off = 32; off > 0; off >>= 1) ss += __shfl_xor(ss, off, 64);
    if (lane == 0) norms[n] = ss;
    float2 z; z.x = 0.f; z.y = 0.f;
    ((float2*)(outz + (size_t)n * 128))[lane] = z;
  } else if (b < 13784) {
    cnt[(b - 13588) * 256 + t] = 0;                // SCAN_N
  } else {
    if (t < 16) esum[t] = 0.f;
  }
}

// ---- P2: g2(384) | energy+hist(1250) ----
__global__ __launch_bounds__(256) void k_prep2(
    const float* __restrict__ Phi, const float* __restrict__ M,
    float* __restrict__ G2, __hip_bfloat16* __restrict__ G2b,
    const float* __restrict__ norms, const float* __restrict__ eattr,
    const float* __restrict__ ett, const int* __restrict__ eidx,
    float* __restrict__ energies, float* __restrict__ esum,
    int* __restrict__ cnt) {
  const int t = threadIdx.x;
  const int b = blockIdx.x;
  if (b < 384) {
    int idx = b * 256 + t;                         // 98304
    int slot = idx >> 7, j2 = idx & 127;
    float acc = 0.f;
    for (int j1 = 0; j1 < 128; ++j1)
      acc = fmaf(Phi[slot * 128 + j1], M[j1 * 128 + j2], acc);
    G2[idx] = acc;
    int k = slot >> 8, s = slot & 255;
    int kc = s >> 5, quad = (s & 31) >> 3, jj = s & 7;
    G2b[((((k * 8 + kc) * 8 + (j2 >> 4)) * 64) + quad * 16 + (j2 & 15)) * 8 + jj] =
        __float2bfloat16(acc);
  } else {
    int e = (b - 384) * 256 + t;
    float ss = norms[eidx[e]];
    const float4* a4 = (const float4*)(eattr + (size_t)e * 32);
#pragma unroll
    for (int i = 0; i < 8; ++i) {
      float4 v = a4[i];
      ss += v.x * v.x + v.y * v.y + v.z * v.z + v.w * v.w;
    }
    const float4* t4 = (const float4*)(ett + (size_t)e * 32);
#pragma unroll
    for (int i = 0; i < 8; ++i) {
      float4 v = t4[i];
      ss += v.x * v.x + v.y * v.y + v.z * v.z + v.w * v.w;
    }
    float en = 192.f * ss;
    energies[e] = en;
    float tot = en;
#pragma unroll
    for (int off = 32; off > 0; off >>= 1) tot += __shfl_down(tot, off, 64);
    if ((t & 63) == 0) atomicAdd(esum, tot);
    atomicAdd(&cnt[eidx[NEDGES + e]], 1);          // histogram
  }
}

// ---- P3: small(5) | scanA(196) ----
__global__ __launch_bounds__(256) void k_prep3(
    const float* __restrict__ rb1, const float* __restrict__ ib1,
    const float* __restrict__ fre_b, const float* __restrict__ comb_b,
    const float* __restrict__ lin_w, const float* __restrict__ M,
    const float* __restrict__ G2, float* __restrict__ bb,
    float* __restrict__ gb2, float* __restrict__ ck,
    int* __restrict__ cnt, int* __restrict__ part) {
  __shared__ int sm[256];
  const int t = threadIdx.x;
  const int b = blockIdx.x;
  if (b < 5) {
    int idx = b * 256 + t;                         // 1280
    if (idx < 768) {
      int k = idx >> 8, r = idx & 255;
      bb[idx] = (r >= 128) ? ib1[k * 128 + (r & 127)] : rb1[k * 128 + r];
    } else if (idx < 896) {
      int j2 = idx - 768;
      float acc = 0.f;
      for (int j = 0; j < 128; ++j) acc += fre_b[j] * M[j * 128 + j2];
      for (int tt = 0; tt < 128; ++tt) acc += comb_b[tt] * lin_w[tt * 128 + j2];
      gb2[j2] = acc;
    } else if (idx < 1280) {
      int q = idx - 896;
      int k = q >> 7, j2 = q & 127;
      float acc = 0.f;
      for (int j = 0; j < 128; ++j) {
        float vr = rb1[k * 128 + j];
        vr = fmaxf(vr, 0.f); vr = (vr > LAM) ? vr - LAM : 0.f;
        float vi = ib1[k * 128 + j];
        vi = fmaxf(vi, 0.f); vi = (vi > LAM) ? vi - LAM : 0.f;
        acc += vr * G2[(k * 256 + j) * 128 + j2] + vi * G2[(k * 256 + 128 + j) * 128 + j2];
      }
      ck[k * 128 + j2] = acc;
    }
  } else {
    int blk = b - 5;
    int i = blk * 256 + t;
    int v = (i < NNODES) ? cnt[i] : 0;
    sm[t] = v;
    __syncthreads();
#pragma unroll
    for (int off = 1; off < 256; off <<= 1) {
      int x = (t >= off) ? sm[t - off] : 0;
      __syncthreads();
      sm[t] += x;
      __syncthreads();
    }
    cnt[i] = sm[t] - v;                            // exclusive, in place
    if (t == 255) part[blk] = sm[t];
  }
}

// fused scanB+scanC
__global__ __launch_bounds__(256) void k_scan(const int* __restrict__ cnt,
                                              const int* __restrict__ part,
                                              int* __restrict__ cur) {
  __shared__ int sm[256];
  const int t = threadIdx.x;
  const int b = blockIdx.x;
  sm[t] = (t < b) ? part[t] : 0;
  __syncthreads();
#pragma unroll
  for (int off = 128; off > 0; off >>= 1) {
    if (t < off) sm[t] += sm[t + off];
    __syncthreads();
  }
  cur[b * 256 + t] = cnt[b * 256 + t] + sm[0];
}

__global__ __launch_bounds__(256) void k_fill(const int* __restrict__ eidx,
                                              int* __restrict__ cur,
                                              int* __restrict__ eids) {
  int e = blockIdx.x * 256 + threadIdx.x;
  int pos = atomicAdd(&cur[eidx[NEDGES + e]], 1);
  eids[pos] = e;
}

// ---- main edge kernel: EXACT R5 structure (147.5 us measured — best).
// Persistent 250x20, software-pipelined (meta 3-deep, gather 1 tile ahead,
// lgkm-only barriers), UNSWAPPED mfma(af, bfr), fused accA[4][2], scalar
// Os writes, 4-wave epilogue reduce. Every deviation tried since measured
// worse: split-B +16us (R6), operand-swap +7us (R7), af-hoist +19.5us (R9,
// compiler caps at 128 VGPR with 63KB LDS -> hoist infeasible).
#define XS_STR 200
#define OS_STR 264
#define ZS_STR 130

#define LOADM_PUBLISH(B)                                                       \
  do {                                                                         \
    if (t < 3) tileact[B][t] = 0;                                              \
    if (t < 64) {                                                              \
      eid_s[B][t] = eidA;                                                      \
      srcs[B][t] = srcA;                                                       \
      dsts[B][t] = dstA;                                                       \
      _Pragma("unroll") for (int k = 0; k < NB; ++k) {                         \
        bool m_ = (enA >= lo[k]) && (enA <= hi[k]);                            \
        maskf[B][k][t] = m_ ? 1.f : 0.f;                                       \
        if (m_) atomicOr(&tileact[B][k], 1);                                   \
      }                                                                        \
    }                                                                          \
  } while (0)

// hand-unrolled gather into named regs
#define GATHER(B)                                                              \
  do {                                                                         \
    const int eh = t >> 5, ch = (t & 31) * 4;                                  \
    hr0 = *(const float4*)(hidden + (size_t)srcs[B][eh] * 128 + ch);           \
    hr1 = *(const float4*)(hidden + (size_t)srcs[B][eh + 16] * 128 + ch);      \
    hr2 = *(const float4*)(hidden + (size_t)srcs[B][eh + 32] * 128 + ch);      \
    hr3 = *(const float4*)(hidden + (size_t)srcs[B][eh + 48] * 128 + ch);      \
    const int ea = t >> 4, q = t & 15;                                         \
    const float* p0 = (q < 8) ? eattr + (size_t)eid_s[B][ea] * 32 + q * 4      \
                              : ett + (size_t)eid_s[B][ea] * 32 + (q - 8) * 4; \
    ar0 = *(const float4*)p0;                                                  \
    const float* p1 = (q < 8) ? eattr + (size_t)eid_s[B][ea + 32] * 32 + q * 4 \
                              : ett + (size_t)eid_s[B][ea + 32] * 32 + (q - 8) * 4; \
    ar1 = *(const float4*)p1;                                                  \
  } while (0)

#define WRITEX()                                                               \
  do {                                                                         \
    const int eh = t >> 5, ch = (t & 31) * 4;                                  \
    unsigned* p;                                                               \
    p = (unsigned*)&Xs[eh * XS_STR + ch];                                      \
    p[0] = pk2(hr0.x, hr0.y); p[1] = pk2(hr0.z, hr0.w);                        \
    p = (unsigned*)&Xs[(eh + 16) * XS_STR + ch];                               \
    p[0] = pk2(hr1.x, hr1.y); p[1] = pk2(hr1.z, hr1.w);                        \
    p = (unsigned*)&Xs[(eh + 32) * XS_STR + ch];                               \
    p[0] = pk2(hr2.x, hr2.y); p[1] = pk2(hr2.z, hr2.w);                        \
    p = (unsigned*)&Xs[(eh + 48) * XS_STR + ch];                               \
    p[0] = pk2(hr3.x, hr3.y); p[1] = pk2(hr3.z, hr3.w);                        \
    const int ea = t >> 4, q4 = (t & 15) * 4;                                  \
    p = (unsigned*)&Xs[ea * XS_STR + 128 + q4];                                \
    p[0] = pk2(ar0.x, ar0.y); p[1] = pk2(ar0.z, ar0.w);                        \
    p = (unsigned*)&Xs[(ea + 32) * XS_STR + 128 + q4];                         \
    p[0] = pk2(ar1.x, ar1.y); p[1] = pk2(ar1.z, ar1.w);                        \
  } while (0)

__global__ __launch_bounds__(512, 2) void k_edges(
    const float* __restrict__ hidden, const float* __restrict__ eattr,
    const float* __restrict__ ett, const float* __restrict__ alpha,
    const int* __restrict__ eidx, const int* __restrict__ eids,
    const __hip_bfloat16* __restrict__ Wb, const __hip_bfloat16* __restrict__ G2b,
    const float* __restrict__ bb, const float* __restrict__ gb2,
    const float* __restrict__ ck, const float* __restrict__ energies,
    const float* __restrict__ esum, float* __restrict__ accum) {
  // Xs (25600 B) + Os (33792 B) live through the band loop; Zs (33280 B)
  // reuses the same region after the final band.
  __shared__ __align__(16) char smem[64 * XS_STR * 2 + 64 * OS_STR * 2];
  short* Xs = (short*)smem;
  short* Os = (short*)(smem + 64 * XS_STR * 2);
  float* Zs = (float*)smem;
  __shared__ float maskf[2][3][64];
  __shared__ int eid_s[2][64], srcs[2][64], dsts[2][64];
  __shared__ int tileact[2][3];

  const int t = threadIdx.x;
  const int lane = t & 63, w = t >> 6;
  const int quad = lane >> 4, lc = lane & 15;
  const int tile = blockIdx.x;

  float lo[NB], hi[NB];
  {
    const float es = *esum;
#pragma unroll
    for (int k = 0; k < NB; ++k) {
      float a = alpha[k];
      float factor = (2.f * (k + 1) - 1.f) / (2.f * NB);
      float Q = a * factor * es;
      float bw = es / (a * (2.f * NB));
      lo[k] = Q - bw;
      hi[k] = Q + bw;
    }
  }

  float4 hr0, hr1, hr2, hr3, ar0, ar1;
  int eidA = 0, srcA = 0, dstA = 0, eidB = 0;
  float enA = 0.f;

  // prologue: meta(tile0) -> buf0; meta(tile1) -> regs; eid(tile2) -> reg
  if (t < 64) {
    int e_ = eids[tile * 64 + t];
    eidA = e_; srcA = eidx[e_]; dstA = eidx[NEDGES + e_]; enA = energies[e_];
  }
  LOADM_PUBLISH(0);
  if (t < 64) {
    int e_ = eids[(tile + EGRID) * 64 + t];
    eidA = e_; srcA = eidx[e_]; dstA = eidx[NEDGES + e_]; enA = energies[e_];
    eidB = eids[(tile + 2 * EGRID) * 64 + t];
  }
  bar_lds();
  GATHER(0);

#pragma unroll 1
  for (int ti = 0; ti < EITER; ++ti) {
    const int cb = ti & 1;
    WRITEX();                                       // consume regs for tile ti
    if (ti + 1 < EITER) LOADM_PUBLISH(cb ^ 1);      // publish meta(ti+1)
    if (t < 64) {
      if (ti + 2 < EITER) {                         // issue meta(ti+2) -> regs
        eidA = eidB;
        srcA = eidx[eidB]; dstA = eidx[NEDGES + eidB]; enA = energies[eidB];
      }
      if (ti + 3 < EITER)                           // issue eid(ti+3) -> reg
        eidB = eids[(tile + (ti + 3) * EGRID) * 64 + t];
    }
    bar_lds();

    v4f acc2[4];
#pragma unroll
    for (int mt = 0; mt < 4; ++mt)
#pragma unroll
      for (int r = 0; r < 4; ++r) acc2[mt][r] = 0.f;

    for (int k = 0; k < NB; ++k) {
      if (!tileact[cb][k]) continue;                // block-uniform
      v4f accA[4][2];
#pragma unroll
      for (int mt = 0; mt < 4; ++mt)
#pragma unroll
        for (int n = 0; n < 2; ++n)
#pragma unroll
          for (int r = 0; r < 4; ++r) accA[mt][n][r] = 0.f;

#pragma unroll
      for (int kc = 0; kc < 6; ++kc) {
        v8s af[4];
#pragma unroll
        for (int mt = 0; mt < 4; ++mt)
          af[mt] = *(const v8s*)&Xs[(mt * 16 + lc) * XS_STR + kc * 32 + quad * 8];
        const __hip_bfloat16* wp = Wb + ((((k * 6 + kc) * 16 + 2 * w) * 64) + lane) * 8;
#pragma unroll
        for (int ntl = 0; ntl < 2; ++ntl) {
          v8s bfr = *(const v8s*)(const void*)(wp + ntl * 512);
#pragma unroll
          for (int mt = 0; mt < 4; ++mt)
            accA[mt][ntl] =
                __builtin_amdgcn_mfma_f32_16x16x32_bf16(af[mt], bfr, accA[mt][ntl], 0, 0, 0);
        }
      }
      bar_lds();  // protect Os WAR vs previous band's stage B reads
      // nonlinearity -> Os (bf16)
#pragma unroll
      for (int mt = 0; mt < 4; ++mt)
#pragma unroll
        for (int ntl = 0; ntl < 2; ++ntl) {
          int col = w * 32 + ntl * 16 + lc;
          float bbv = bb[k * 256 + col];
#pragma unroll
          for (int reg = 0; reg < 4; ++reg) {
            int row = mt * 16 + quad * 4 + reg;
            float mk = maskf[cb][k][row];
            float v = fmaf(mk, accA[mt][ntl][reg], bbv);
            v = fmaxf(v, 0.f);
            v = (v > LAM) ? v - LAM : 0.f;
            __hip_bfloat16 h = __float2bfloat16(v);
            Os[row * OS_STR + col] = *reinterpret_cast<short*>(&h);
          }
        }
      bar_lds();
      // stage B: acc2 += O' @ G2_band ; wave w -> cols w*16..w*16+15
#pragma unroll
      for (int kc = 0; kc < 8; ++kc) {
        v8s of[4];
#pragma unroll
        for (int mt = 0; mt < 4; ++mt)
          of[mt] = *(const v8s*)&Os[(mt * 16 + lc) * OS_STR + kc * 32 + quad * 8];
        const __hip_bfloat16* gp = G2b + ((((k * 8 + kc) * 8 + w) * 64) + lane) * 8;
        v8s bfr = *(const v8s*)(const void*)gp;
#pragma unroll
        for (int mt = 0; mt < 4; ++mt)
          acc2[mt] = __builtin_amdgcn_mfma_f32_16x16x32_bf16(of[mt], bfr, acc2[mt], 0, 0, 0);
      }
    }

    // prefetch next tile's gather into regs; epilogue is the latency cover
    if (ti + 1 < EITER) GATHER(cb ^ 1);

    // ---- epilogue: z -> Zs (LDS), then segmented reduce (4 waves) + atomics
    bar_lds();                                      // Xs/Os reads done; reuse as Zs
    {
      int col = w * 16 + lc;
      float base = gb2[col];
#pragma unroll
      for (int k = 0; k < NB; ++k)
        if (!tileact[cb][k]) base += ck[k * 128 + col];
#pragma unroll
      for (int mt = 0; mt < 4; ++mt)
#pragma unroll
        for (int reg = 0; reg < 4; ++reg) {
          int row = mt * 16 + quad * 4 + reg;
          Zs[row * ZS_STR + col] = acc2[mt][reg] + base;
        }
    }
    bar_lds();
    if (w < 4) {
      int c = 2 * lane;
      int r0 = w * 16;
      float s0 = 0.f, s1 = 0.f;
#pragma unroll
      for (int r = 0; r < 16; ++r) {
        int row = r0 + r;
        s0 += Zs[row * ZS_STR + c];
        s1 += Zs[row * ZS_STR + c + 1];
        int d = dsts[cb][row];
        if (r == 15 || dsts[cb][row + 1] != d) {
          atomic2(accum + (size_t)d * 128 + c, s0, s1);
          s0 = 0.f; s1 = 0.f;
        }
      }
    }
    if (ti + 1 < EITER) bar_lds();                  // Zs reads done before next WRITEX
  }
}

// node kernel: MFMA bf16 boundary@lin_w (+edge accum +lin_b) -> LN -> relu.
__global__ __launch_bounds__(256) void k_nodes(
    const float* __restrict__ boundary, const __hip_bfloat16* __restrict__ lwb,
    const float* __restrict__ lin_b, const float* __restrict__ ln_g,
    const float* __restrict__ ln_b, float* __restrict__ out) {
  __shared__ __align__(16) short Bs[64 * 136];     // 17408 B
  __shared__ __align__(16) float Zs[64 * 132];     // 33792 B
  const int t = threadIdx.x;
  const int w = t >> 6, lane = t & 63;
  const int quad = lane >> 4, lc = lane & 15;
  const int n0 = blockIdx.x * 64;
  // stage boundary -> bf16 (rows beyond NNODES zeroed)
#pragma unroll
  for (int it = 0; it < 8; ++it) {
    int fi = it * 256 + t;                         // 2048 float4 slots
    int row = fi >> 5, c4 = fi & 31;
    float4 v = make_float4(0.f, 0.f, 0.f, 0.f);
    if (n0 + row < NNODES)
      v = *(const float4*)(boundary + (size_t)(n0 + row) * 128 + c4 * 4);
    v2u u; u.x = pk2(v.x, v.y); u.y = pk2(v.z, v.w);
    *(v2u*)&Bs[row * 136 + c4 * 4] = u;
  }
  __syncthreads();
  const int we = w >> 1, wc = w & 1;               // 32 rows x 64 cols per wave
  v4f acc[2][4];
#pragma unroll
  for (int m2 = 0; m2 < 2; ++m2)
#pragma unroll
    for (int ct = 0; ct < 4; ++ct)
#pragma unroll
      for (int r = 0; r < 4; ++r) acc[m2][ct][r] = 0.f;
#pragma unroll
  for (int kc = 0; kc < 4; ++kc) {
    v8s b0 = *(const v8s*)&Bs[(we * 32 + lc) * 136 + kc * 32 + quad * 8];
    v8s b1 = *(const v8s*)&Bs[(we * 32 + 16 + lc) * 136 + kc * 32 + quad * 8];
#pragma unroll
    for (int ct = 0; ct < 4; ++ct) {
      v8s af = *(const v8s*)(const void*)(
          lwb + (((kc * 8 + (wc * 4 + ct)) * 64) + lane) * 8);
      acc[0][ct] = __builtin_amdgcn_mfma_f32_16x16x32_bf16(af, b0, acc[0][ct], 0, 0, 0);
      acc[1][ct] = __builtin_amdgcn_mfma_f32_16x16x32_bf16(af, b1, acc[1][ct], 0, 0, 0);
    }
  }
#pragma unroll
  for (int m2 = 0; m2 < 2; ++m2)
#pragma unroll
    for (int ct = 0; ct < 4; ++ct) {
      const int colb = wc * 64 + ct * 16 + quad * 4;
      const int row = we * 32 + m2 * 16 + lc;
      float4 z;
      z.x = acc[m2][ct][0]; z.y = acc[m2][ct][1];
      z.z = acc[m2][ct][2]; z.w = acc[m2][ct][3];
      *(float4*)&Zs[row * 132 + colb] = z;
    }
  __syncthreads();
  // LN: wave handles 16 nodes; lane owns cols 2*lane, 2*lane+1
  const int c = 2 * lane;
  const float2 lb = *(const float2*)&lin_b[c];
  const float2 gg = *(const float2*)&ln_g[c];
  const float2 bbv = *(const float2*)&ln_b[c];
#pragma unroll 1
  for (int i = 0; i < 16; ++i) {
    int row = w * 16 + i;
    int n = n0 + row;
    if (n >= NNODES) break;
    const float2 z = *(const float2*)&Zs[row * 132 + c];
    const float2 ob = *(const float2*)&out[(size_t)n * 128 + c];
    float a0 = z.x + ob.x + lb.x;
    float a1 = z.y + ob.y + lb.y;
    float s = a0 + a1, sq = a0 * a0 + a1 * a1;
#pragma unroll
    for (int off = 32; off > 0; off >>= 1) {
      s += __shfl_xor(s, off, 64);
      sq += __shfl_xor(sq, off, 64);
    }
    float mu = s * (1.f / 128.f);
    float var = sq * (1.f / 128.f) - mu * mu;
    float rs = 1.f / sqrtf(var + LN_EPS);
    float2 o;
    o.x = fmaxf((a0 - mu) * rs * gg.x + bbv.x, 0.f);
    o.y = fmaxf((a1 - mu) * rs * gg.y + bbv.y, 0.f);
    *(float2*)&out[(size_t)n * 128 + c] = o;
  }
}

extern "C" void kernel_launch(void* const* d_in, const int* in_sizes, int n_in,
                              void* d_out, int out_size, void* d_ws, size_t ws_size,
                              hipStream_t stream) {
  const float* hidden   = (const float*)d_in[0];
  const float* eattr    = (const float*)d_in[1];
  const float* ett      = (const float*)d_in[2];
  const float* boundary = (const float*)d_in[3];
  const float* alpha    = (const float*)d_in[4];
  const float* r1       = (const float*)d_in[5];
  const float* i1       = (const float*)d_in[6];
  const float* rb1      = (const float*)d_in[7];
  const float* ib1      = (const float*)d_in[8];
  const float* fre_w    = (const float*)d_in[9];
  const float* fre_b    = (const float*)d_in[10];
  const float* comb_w   = (const float*)d_in[11];
  const float* comb_b   = (const float*)d_in[12];
  const float* lin_w    = (const float*)d_in[13];
  const float* lin_b    = (const float*)d_in[14];
  const float* ln_g     = (const float*)d_in[15];
  const float* ln_b     = (const float*)d_in[16];
  const int*   eidx     = (const int*)d_in[17];
  float* ws  = (float*)d_ws;
  float* out = (float*)d_out;
  __hip_bfloat16* Wb  = (__hip_bfloat16*)(ws + WS_WB);
  __hip_bfloat16* G2b = (__hip_bfloat16*)(ws + WS_G2B);
  __hip_bfloat16* lwb = (__hip_bfloat16*)(ws + WS_LWB);
  int* cnt  = (int*)(ws + WS_CNT);
  int* cur  = (int*)(ws + WS_CUR);
  int* part = (int*)(ws + WS_PART);
  int* eids = (int*)(ws + WS_EIDS);

  k_prep1<<<13785, 256, 0, stream>>>(r1, i1, Wb, comb_w, lin_w, ws + WS_M,
                                     fre_w, ws + WS_PHI, hidden, ws + WS_NORM,
                                     out, cnt, ws + WS_ESUM, lwb);
  k_prep2<<<384 + NEDGES / 256, 256, 0, stream>>>(ws + WS_PHI, ws + WS_M, ws + WS_G2,
                                                  G2b, ws + WS_NORM, eattr, ett, eidx,
                                                  ws + WS_EN, ws + WS_ESUM, cnt);
  k_prep3<<<5 + SCAN_B, 256, 0, stream>>>(rb1, ib1, fre_b, comb_b, lin_w, ws + WS_M,
                                          ws + WS_G2, ws + WS_BB, ws + WS_GB2,
                                          ws + WS_CK, cnt, part);
  k_scan<<<SCAN_B, 256, 0, stream>>>(cnt, part, cur);
  k_fill<<<NEDGES / 256, 256, 0, stream>>>(eidx, cur, eids);
  k_edges<<<EGRID, 512, 0, stream>>>(hidden, eattr, ett, alpha, eidx, eids,
                                     Wb, G2b, ws + WS_BB, ws + WS_GB2,
                                     ws + WS_CK, ws + WS_EN, ws + WS_ESUM, out);
  k_nodes<<<(NNODES + 63) / 64, 256, 0, stream>>>(boundary, lwb, lin_b, ln_g, ln_b, out);
}